// Round 11
// baseline (303.335 us; speedup 1.0000x reference)
//
#include <hip/hip_runtime.h>
#include <hip/hip_bf16.h>

typedef __attribute__((ext_vector_type(8))) short bf16x8;
typedef __attribute__((ext_vector_type(4))) float f32x4;

#define LDSG(g, l) __builtin_amdgcn_global_load_lds(                      \
    (const __attribute__((address_space(1))) void*)(g),                   \
    (__attribute__((address_space(3))) void*)(l), 16, 0, 0)

#define LOG2E 1.44269504088896f
#define RELSC 0.180336880111112f   /* 0.125 * log2(e) */

// ---------------- kernel 1: fp32 -> bf16 convert (hidden + Wq|Wk|Wv) --------
__global__ __launch_bounds__(256) void cvt_kernel(
    const float* __restrict__ hs,
    const float* __restrict__ wq, const float* __restrict__ wk,
    const float* __restrict__ wv,
    __hip_bfloat16* __restrict__ hbf, __hip_bfloat16* __restrict__ wbf)
{
  const int NH = (4 * 1024 * 1024) / 4;   // hidden quads
  const int NW = (1024 * 1024) / 4;       // per-W quads
  int i = blockIdx.x * 256 + threadIdx.x; // exact grid: NH + 3*NW quads
  float4 v;
  __hip_bfloat16* dst;
  if (i < NH) {
    v = ((const float4*)hs)[i];
    dst = hbf + (size_t)i * 4;
  } else {
    int j = i - NH;
    int which = j / NW, r = j - which * NW;
    const float* src = which == 0 ? wq : (which == 1 ? wk : wv);
    v = ((const float4*)src)[r];
    dst = wbf + (size_t)j * 4;
  }
  union { ushort4 u; __hip_bfloat16 b[4]; } o;
  o.b[0] = __float2bfloat16(v.x);
  o.b[1] = __float2bfloat16(v.y);
  o.b[2] = __float2bfloat16(v.z);
  o.b[3] = __float2bfloat16(v.w);
  *((ushort4*)dst) = o.u;
}

// ---------------- kernel 2: QKV GEMM  C[4096][3072] = A[4096][1024] @ W^T ---
// q scaled by 0.125*log2e, stored [b,h,s,d].
// k/v written PRE-FRAGMENTED in MFMA A-operand order per (bh, ktile):
//   K  chunk (ks*4+ct)*64+lane holds K[k=ct*16+(lane&15)][d=ks*32+(lane>>4)*8+e]
//   V^T chunk (ks*4+dt)*64+lane holds V[k=ks*32+(lane>>4)*8+e][d=dt*16+(lane&15)]
// so attention loads are fully contiguous 1KB instructions.
__global__ __launch_bounds__(256) void qkv_gemm(
    const __hip_bfloat16* __restrict__ A,  // [4096][1024]
    const __hip_bfloat16* __restrict__ W,  // [3072][1024] (q,k,v stacked)
    const float* __restrict__ bq, const float* __restrict__ bk,
    const float* __restrict__ bv,
    __hip_bfloat16* __restrict__ qo, __hip_bfloat16* __restrict__ ko,
    __hip_bfloat16* __restrict__ vo)
{
  const int K = 1024;
  __shared__ __hip_bfloat16 As[128 * 64];
  __shared__ __hip_bfloat16 Bs[128 * 64];
  const int bid = blockIdx.x;
  const int bm = bid & 31, bn = bid >> 5;
  const int m0 = bm * 128, n0 = bn * 128;
  const int tid = threadIdx.x, wid = tid >> 6, lane = tid & 63;
  const int wm = wid >> 1, wn = wid & 1;

  f32x4 acc[4][4] = {};

  const int srow = lane >> 3;              // 0..7 (row within 8-row group)
  const int schunk = (lane & 7) ^ srow;    // swizzled 16B-chunk in row

  for (int k0 = 0; k0 < K; k0 += 64) {
#pragma unroll
    for (int p = 0; p < 4; ++p) {
      int r = (wid * 4 + p) * 8 + srow;    // 0..127
      LDSG(&A[(size_t)(m0 + r) * K + k0 + schunk * 8], &As[(wid * 4 + p) * 512]);
      LDSG(&W[(size_t)(n0 + r) * K + k0 + schunk * 8], &Bs[(wid * 4 + p) * 512]);
    }
    __syncthreads();
#pragma unroll
    for (int ks = 0; ks < 2; ++ks) {
      bf16x8 af[4], bfr[4];
#pragma unroll
      for (int mi = 0; mi < 4; ++mi) {
        int row = wm * 64 + mi * 16 + (lane & 15);
        int slot = (ks * 4 + (lane >> 4)) ^ (lane & 7);
        af[mi] = *(const bf16x8*)((const char*)As + row * 128 + slot * 16);
      }
#pragma unroll
      for (int ni = 0; ni < 4; ++ni) {
        int row = wn * 64 + ni * 16 + (lane & 15);
        int slot = (ks * 4 + (lane >> 4)) ^ (lane & 7);
        bfr[ni] = *(const bf16x8*)((const char*)Bs + row * 128 + slot * 16);
      }
#pragma unroll
      for (int mi = 0; mi < 4; ++mi)
#pragma unroll
        for (int ni = 0; ni < 4; ++ni)
          acc[mi][ni] = __builtin_amdgcn_mfma_f32_16x16x32_bf16(
              af[mi], bfr[ni], acc[mi][ni], 0, 0, 0);
    }
    __syncthreads();
  }

  // epilogue. C/D layout: col = lane&15, row = (lane>>4)*4+j.
#pragma unroll
  for (int ni = 0; ni < 4; ++ni) {
    int n = n0 + wn * 64 + ni * 16 + (lane & 15);
    int which = n >> 10;         // 0=q 1=k 2=v (uniform per block)
    int h = (n >> 6) & 15;
    int d = n & 63;
    const float* bias = which == 0 ? bq : (which == 1 ? bk : bv);
    float bval = bias[n & 1023];
    if (which == 0) {
      // q: [b,h,s,d], pre-scaled by 0.125*log2e
#pragma unroll
      for (int mi = 0; mi < 4; ++mi) {
#pragma unroll
        for (int j = 0; j < 4; ++j) {
          int m = m0 + wm * 64 + mi * 16 + (lane >> 4) * 4 + j;
          int b = m >> 10, s = m & 1023;
          float val = (acc[mi][ni][j] + bval) * RELSC;
          qo[(((size_t)(b * 16 + h) << 10) + s) * 64 + d] = __float2bfloat16(val);
        }
      }
    } else if (which == 1) {
      // K fragment store (scalar scatter)
      int dks = d >> 5, dlg = (d >> 3) & 3, de = d & 7;
#pragma unroll
      for (int mi = 0; mi < 4; ++mi) {
#pragma unroll
        for (int j = 0; j < 4; ++j) {
          int m = m0 + wm * 64 + mi * 16 + (lane >> 4) * 4 + j;
          int b = m >> 10, s = m & 1023;
          size_t idx = ((((size_t)(b * 16 + h)) * 16 + (s >> 6)) * 512 +
                        (size_t)((dks * 4 + ((s >> 4) & 3)) * 64 + (s & 15) +
                                 16 * dlg)) * 8 + de;
          ko[idx] = __float2bfloat16(acc[mi][ni][j] + bval);
        }
      }
    } else {
      // V^T fragment store (ushort4: 4 consecutive k -> consecutive e)
      int dt = d >> 4, dl15 = d & 15;
#pragma unroll
      for (int mi = 0; mi < 4; ++mi) {
        int m = m0 + wm * 64 + mi * 16 + (lane >> 4) * 4;  // k0 (mod 4 == 0)
        int b = m >> 10, k = m & 1023;
        int kt = k >> 6, kks = (k >> 5) & 1, klg = (k >> 3) & 3, ke = k & 7;
        union { ushort4 u; __hip_bfloat16 bb[4]; } o;
#pragma unroll
        for (int j = 0; j < 4; ++j)
          o.bb[j] = __float2bfloat16(acc[mi][ni][j] + bval);
        size_t idx = ((((size_t)(b * 16 + h)) * 16 + kt) * 512 +
                      (size_t)((kks * 4 + dt) * 64 + dl15 + 16 * klg)) * 8 + ke;
        *(ushort4*)&vo[idx] = o.u;
      }
    }
  }
}

// ---------------- kernel 3: panel-staged attention ---------------------------
// grid 8192 = 64 bh x 128 q-tiles of 8 rows; 384 threads = 6 waves.
// Waves 4-5 (streamers): stage the block's ENTIRE rel panel (8 rows x 4KB x
// 2 rels = 64KB) into LDS in per-row SEQUENTIAL bursts (4x 1KB LDSG per
// row-half -> 2KB DRAM runs, copy-bench pattern), two halves with barriers
// A/B. Waves 0-3 (consumers): k-split — wave w computes tiles {w,w+4} (half
// 0) then {w+8,w+12} (half 1); fixed-max softmax means partial O / partial
// denominators just SUM across waves (one LDS reduction at the end, no
// rescale). Consumers touch only L2-resident K/V frags + LDS -> vmcnt
// domains fully separated from the rel stream.
__global__ __launch_bounds__(384, 3) void attn_kernel(
    const __hip_bfloat16* __restrict__ qg, const __hip_bfloat16* __restrict__ kf,
    const __hip_bfloat16* __restrict__ vf,
    const float* __restrict__ rel1, const float* __restrict__ rel2,
    const float* __restrict__ mask, float* __restrict__ out)
{
  __shared__ float Rp[2][8][1024];          // rel panel, 64 KB, chunk-swizzled
  __shared__ float Ml[1024];                // mask*log2e - 32, 4 KB
  __shared__ __hip_bfloat16 Ps[4][16 * 64]; // P bounce / O-partials, 8 KB
  __shared__ float Lr[4][16];               // denominator partials, 256 B

  const int bid = blockIdx.x;
  const int bh = bid & 63, qt = bid >> 6;   // bid%8==bh%8 -> bh pinned to XCD
  const int b = bh >> 4, h = bh & 15;
  const int tid = threadIdx.x, wid = tid >> 6, lane = tid & 63;
  const int lg = lane >> 4, ln15 = lane & 15;

  const size_t qbase = (size_t)bh << 16;    // bh * 1024 * 64
  const size_t fbase = (size_t)bh << 16;    // frag elems per bh
  const int q0 = qt * 8;

  if (wid >= 4) {
    // ------------------------- streamer waves -----------------------------
    const int s = wid - 4;                  // 0,1
    const float* relw0 = rel1 + ((size_t)bh << 20);
    const float* relw1 = rel2 + ((size_t)bh << 20);

    // mask: 128 threads x 8 floats; Ml = mask*log2e - 32
    {
      int i = s * 64 + lane;                // 0..127
      float4 m0 = *(const float4*)&mask[((size_t)b << 10) + i * 8];
      float4 m1 = *(const float4*)&mask[((size_t)b << 10) + i * 8 + 4];
      float4 s0, s1;
      s0.x = m0.x * LOG2E - 32.0f; s0.y = m0.y * LOG2E - 32.0f;
      s0.z = m0.z * LOG2E - 32.0f; s0.w = m0.w * LOG2E - 32.0f;
      s1.x = m1.x * LOG2E - 32.0f; s1.y = m1.y * LOG2E - 32.0f;
      s1.z = m1.z * LOG2E - 32.0f; s1.w = m1.w * LOG2E - 32.0f;
      *(float4*)&Ml[i * 8] = s0;
      *(float4*)&Ml[i * 8 + 4] = s1;
    }

    // stage half H: rows 4s..4s+3, both rels; per (row,rel): 2x sequential
    // 1KB LDSG. Source chunk pre-swizzled (low-3 ^= row) so the score-phase
    // ds_read_b128 across 8 rows is bank-conflict-free; LDS dest stays linear.
#define SHALF(H) do {                                                       \
    _Pragma("unroll") for (int rr = 0; rr < 4; ++rr) {                      \
      int r = s * 4 + rr;                                                   \
      int soff = ((lane & 56) | ((lane ^ r) & 7)) * 4;                      \
      _Pragma("unroll") for (int P = 0; P < 2; ++P) {                       \
        LDSG(&relw0[(size_t)(q0 + r) * 1024 + (H) * 512 + P * 256 + soff],  \
             &Rp[0][r][(H) * 512 + P * 256]);                               \
        LDSG(&relw1[(size_t)(q0 + r) * 1024 + (H) * 512 + P * 256 + soff],  \
             &Rp[1][r][(H) * 512 + P * 256]);                               \
      }                                                                     \
    } } while (0)

    SHALF(0);
    asm volatile("s_waitcnt vmcnt(0) lgkmcnt(0)" ::: "memory");
    __builtin_amdgcn_s_barrier();           // barrier A: half 0 + mask ready
    SHALF(1);
    asm volatile("s_waitcnt vmcnt(0)" ::: "memory");
    __builtin_amdgcn_s_barrier();           // barrier B: half 1 ready
    __builtin_amdgcn_s_barrier();           // barrier C (consumer reduction)
    return;
  }

  // -------------------------- consumer waves ------------------------------
  // Q as B-operand: col=ln15 (rows 8-15 duplicate rows 0-7, discarded at end)
  const int qrow = q0 + (ln15 & 7);
  bf16x8 qf[2];
  qf[0] = *(const bf16x8*)&qg[qbase + (size_t)qrow * 64 + lg * 8];
  qf[1] = *(const bf16x8*)&qg[qbase + (size_t)qrow * 64 + 32 + lg * 8];

  f32x4 accO[4] = {};
  float lrun = 0.f;
  const int r_ = ln15 & 7;

#define CB(T) do {                                                          \
    bf16x8 kfr[8], vfr[8];                                                  \
    _Pragma("unroll") for (int i = 0; i < 8; ++i)                           \
      kfr[i] = *(const bf16x8*)&kf[fbase + (size_t)(T) * 4096 + i * 512 +   \
                                   lane * 8];                               \
    _Pragma("unroll") for (int i = 0; i < 8; ++i)                           \
      vfr[i] = *(const bf16x8*)&vf[fbase + (size_t)(T) * 4096 + i * 512 +   \
                                   lane * 8];                               \
    f32x4 st[4] = {};                                                       \
    _Pragma("unroll") for (int ks = 0; ks < 2; ++ks)                        \
      _Pragma("unroll") for (int ct = 0; ct < 4; ++ct)                      \
        st[ct] = __builtin_amdgcn_mfma_f32_16x16x32_bf16(                   \
            kfr[ks * 4 + ct], qf[ks], st[ct], 0, 0, 0);                     \
    float p_[4][4];                                                         \
    _Pragma("unroll") for (int ct = 0; ct < 4; ++ct) {                      \
      int cc = (T) * 16 + ct * 4 + lg;                                      \
      int phys = (cc & ~7) | ((cc ^ r_) & 7);                               \
      float4 rv1 = *(const float4*)((const char*)&Rp[0][r_][0] + phys * 16);\
      float4 rv2 = *(const float4*)((const char*)&Rp[1][r_][0] + phys * 16);\
      float4 mv = *(const float4*)&Ml[(T) * 64 + ct * 16 + lg * 4];         \
      _Pragma("unroll") for (int j = 0; j < 4; ++j) {                       \
        float sv = st[ct][j] +                                              \
                   RELSC * (((const float*)&rv1)[j] +                       \
                            ((const float*)&rv2)[j]) +                      \
                   ((const float*)&mv)[j];                                  \
        float e = __builtin_amdgcn_exp2f(sv);                               \
        p_[ct][j] = e; lrun += e;                                           \
      }                                                                     \
    }                                                                       \
    __hip_bfloat16* Pw = &Ps[wid][0];                                       \
    _Pragma("unroll") for (int ct = 0; ct < 4; ++ct) {                      \
      union { ushort4 u; __hip_bfloat16 bb[4]; } w;                         \
      _Pragma("unroll") for (int j = 0; j < 4; ++j)                         \
        w.bb[j] = __float2bfloat16(p_[ct][j]);                              \
      *(ushort4*)((char*)Pw + ln15 * 128 +                                  \
                  ((ct * 32 + lg * 8) ^ ((ln15 & 7) << 4))) = w.u;          \
    }                                                                       \
    bf16x8 pt[2];                                                           \
    pt[0] = *(const bf16x8*)((const char*)Pw + ln15 * 128 +                 \
                             ((lg * 16) ^ ((ln15 & 7) << 4)));              \
    pt[1] = *(const bf16x8*)((const char*)Pw + ln15 * 128 +                 \
                             ((64 + lg * 16) ^ ((ln15 & 7) << 4)));         \
    _Pragma("unroll") for (int ks = 0; ks < 2; ++ks)                        \
      _Pragma("unroll") for (int dt = 0; dt < 4; ++dt)                      \
        accO[dt] = __builtin_amdgcn_mfma_f32_16x16x32_bf16(                 \
            vfr[ks * 4 + dt], pt[ks], accO[dt], 0, 0, 0);                   \
  } while (0)

  __builtin_amdgcn_s_barrier();             // barrier A (half 0 + mask ready)
  CB(wid);
  CB(wid + 4);
  __builtin_amdgcn_s_barrier();             // barrier B (half 1 ready)
  CB(wid + 8);
  CB(wid + 12);

  // partial denominator: sum the 4 lg-groups for each q column
  lrun += __shfl_xor(lrun, 16, 64);
  lrun += __shfl_xor(lrun, 32, 64);
  if (lane < 16) Lr[wid][lane] = lrun;

  // partial O into this wave's Ps region (8 q x 64 d fp32 = 2 KB, exact fit)
  {
    float* Od = (float*)&Ps[wid][0];
    if (ln15 < 8) {
#pragma unroll
      for (int dt = 0; dt < 4; ++dt)
        *(f32x4*)&Od[ln15 * 64 + dt * 16 + lg * 4] = accO[dt];
    }
  }
  asm volatile("s_waitcnt lgkmcnt(0)" ::: "memory");
  __builtin_amdgcn_s_barrier();             // barrier C

  // final cross-wave reduction + output: wave w writes q-rows {2w, 2w+1}
  {
    int q = 2 * wid + (lane >> 5);
    int d = (lane & 31) * 2;
    float ax = 0.f, ay = 0.f, lr = 0.f;
#pragma unroll
    for (int w = 0; w < 4; ++w) {
      const float* Ow = (const float*)&Ps[w][0];
      float2 v = *(const float2*)&Ow[q * 64 + d];
      ax += v.x; ay += v.y;
      lr += Lr[w][q];
    }
    float rl = 1.0f / lr;
    float2 o; o.x = ax * rl; o.y = ay * rl;
    *(float2*)&out[((size_t)(b * 1024 + q0 + q)) * 1024 + h * 64 + d] = o;
  }
}

// ---------------------------------------------------------------------------
extern "C" void kernel_launch(void* const* d_in, const int* in_sizes, int n_in,
                              void* d_out, int out_size, void* d_ws,
                              size_t ws_size, hipStream_t stream) {
  const float* hs   = (const float*)d_in[0];
  const float* mask = (const float*)d_in[1];
  const float* rel1 = (const float*)d_in[2];
  const float* rel2 = (const float*)d_in[3];
  const float* Wq   = (const float*)d_in[4];
  const float* bq   = (const float*)d_in[5];
  const float* Wk   = (const float*)d_in[6];
  const float* bk   = (const float*)d_in[7];
  const float* Wv   = (const float*)d_in[8];
  const float* bv   = (const float*)d_in[9];

  char* ws = (char*)d_ws;
  __hip_bfloat16* hbf = (__hip_bfloat16*)(ws);              // 8 MB
  __hip_bfloat16* wbf = (__hip_bfloat16*)(ws + 8388608);    // 6 MB
  __hip_bfloat16* qb  = (__hip_bfloat16*)(ws + 14680064);   // 8 MB
  __hip_bfloat16* kfb = (__hip_bfloat16*)(ws + 23068672);   // 8 MB (K frag)
  __hip_bfloat16* vfb = (__hip_bfloat16*)(ws + 31457280);   // 8 MB (V^T frag)

  cvt_kernel<<<7168, 256, 0, stream>>>(hs, Wq, Wk, Wv, hbf, wbf);
  qkv_gemm<<<768, 256, 0, stream>>>(hbf, wbf, bq, bk, bv, qb, kfb, vfb);
  attn_kernel<<<8192, 384, 0, stream>>>(qb, kfb, vfb, rel1, rel2, mask,
                                        (float*)d_out);
}